// Round 6
// baseline (1638.513 us; speedup 1.0000x reference)
//
#include <hip/hip_runtime.h>
#include <hip/hip_bf16.h>

#define TT 512
#define NTILE 32
#define BPW 16
#define NTHREADS 512
#define CH 32          // steps per chunk
#define NCH 16         // chunks (512/32)

typedef __bf16 bf16x8 __attribute__((ext_vector_type(8)));
typedef float f32x4 __attribute__((ext_vector_type(4)));
typedef unsigned int uint4v __attribute__((ext_vector_type(4)));

#define MFMA(a, b, c) __builtin_amdgcn_mfma_f32_16x16x32_bf16((a), (b), (c), 0, 0, 0)
// Raw barrier: LDS drain only; global loads stay in flight.
#define BAR() asm volatile("s_waitcnt lgkmcnt(0)\n\ts_barrier" ::: "memory")

__device__ __forceinline__ unsigned short f2bf(float f) {
  unsigned int u = __float_as_uint(f);
  u = u + 0x7FFFu + ((u >> 16) & 1u);
  return (unsigned short)(u >> 16);
}
__device__ __forceinline__ float bf2f(unsigned short s) {
  return __uint_as_float(((unsigned int)s) << 16);
}
__device__ __forceinline__ float sigm(float x) {
  return __builtin_amdgcn_rcpf(1.f + __builtin_amdgcn_exp2f(-1.44269504f * x));
}
__device__ __forceinline__ float tanh_(float x) {
  return 1.f - 2.f * __builtin_amdgcn_rcpf(1.f + __builtin_amdgcn_exp2f(2.88539008f * x));
}
__device__ __forceinline__ float softplus_(float x) {
  if (x > 15.f) return x;
  float e = __builtin_amdgcn_exp2f(1.44269504f * x);
  return 0.69314718f * __builtin_amdgcn_logf(1.f + e);
}

// Pin a fragment in VGPRs: opaque asm output cannot be rematerialized from the
// original load, so the register allocator must keep it live across the scan.
__device__ __forceinline__ bf16x8 pinf(bf16x8 x) {
  uint4v u = __builtin_bit_cast(uint4v, x);
  asm volatile("" : "+v"(u));
  return __builtin_bit_cast(bf16x8, u);
}

// Pack a [512][K] f32 weight matrix into bf16 B-fragment order:
// dst[((tau*ktiles + c)*64 + l)*8 + i] = W[tau*16 + (l&15)][c*32 + 8*(l>>4) + i]
__global__ void pack_w_kern(const float* __restrict__ src, unsigned short* __restrict__ dst,
                            int K, int ktiles) {
  int tid = blockIdx.x * 256 + threadIdx.x;
  int total = 32 * ktiles * 64;
  if (tid >= total) return;
  int l = tid & 63;
  int c = (tid >> 6) % ktiles;
  int tau = tid / (64 * ktiles);
  int n = tau * 16 + (l & 15);
  int k0 = c * 32 + 8 * (l >> 4);
  unsigned short o[8];
#pragma unroll
  for (int i = 0; i < 8; ++i) {
    int k = k0 + i;
    float v = (k < K) ? src[n * K + k] : 0.f;
    o[i] = f2bf(v);
  }
  *(uint4v*)(dst + (size_t)tid * 8) = *(const uint4v*)o;
}

// Build x0 (concat cont feats + embeddings), bf16, A-fragment order, K padded 22->32.
__global__ void pack_x0_kern(const float* __restrict__ xc, const int* __restrict__ idxs,
                             const int* __restrict__ idxi, const float* __restrict__ es,
                             const float* __restrict__ ei, unsigned short* __restrict__ dst) {
  int tid = blockIdx.x * 256 + threadIdx.x;
  if (tid >= TT * NTILE * 64) return;
  int l = tid & 63;
  int b = (tid >> 6) & 31;
  int t = tid >> 11;
  int bi = b * BPW + (l & 15);
  int k0 = 8 * (l >> 4);
  int si = idxs[bi * TT + t];
  int it = idxi[bi * TT + t];
  const float* xr = xc + ((size_t)bi * TT + t) * 12;
  unsigned short o[8];
#pragma unroll
  for (int i = 0; i < 8; ++i) {
    int k = k0 + i;
    float v;
    if (k < 12)      v = xr[k];
    else if (k < 17) v = es[si * 5 + (k - 12)];
    else if (k < 22) v = ei[it * 5 + (k - 17)];
    else             v = 0.f;
    o[i] = f2bf(v);
  }
  *(uint4v*)(dst + (size_t)tid * 8) = *(const uint4v*)o;
}

// Gaussian head for step slot `tt` (reads h2 from buf slot tt). Waves 0-3 only.
__device__ __forceinline__ void head_step(
    int b, int t, const unsigned short* slotbase,
    const float* wmS, const float* waS, const float* vS,
    float bmv, float bav, float* out) {
  const int tid = threadIdx.x;
  if (tid >= 256) return;
  int s_ = tid & 7, hd = (tid >> 3) & 1, bi = tid >> 4;
  const float* wv = hd ? waS : wmS;
  const unsigned short* hrow = slotbase + bi * 136 + s_ * 16;
  float part = 0.f;
#pragma unroll
  for (int kk = 0; kk < 16; ++kk) part += bf2f(hrow[kk]) * wv[s_ * 16 + kk];
  part += __shfl_xor(part, 1);
  part += __shfl_xor(part, 2);
  part += __shfl_xor(part, 4);
  if (s_ == 0) {
    float val = part + (hd ? bav : bmv);
    if (hd) val = softplus_(val);
    out[(((size_t)(b * BPW + bi)) * TT + t) * 2 + hd] = val * vS[bi];
  }
}

// One layer's scan over one chunk of CH steps. Weights register-resident (pinned)
// for the whole chunk. In-place LDS chunk buffer: slot tt holds this layer's
// input until step tt, then this layer's output h(tt). One raw barrier per step.
template<int L>
__device__ __forceinline__ void scan_chunk(
    int k, int b, const unsigned short* wp_ih, const unsigned short* wp_hh,
    const unsigned short* x0p, unsigned short* buf, unsigned short* carry,
    float (&cc)[4], const float (&bia)[4],
    const float* wmS, const float* waS, const float* vS,
    float bmv, float bav, float* out) {
  const int tid = threadIdx.x;
  const int l = tid & 63;
  const int w = tid >> 6;
  const int j = w * 16 + (l & 15);
  const int row0 = (l >> 4) * 4;
  const int fragoff = (l & 15) * 136 + 8 * (l >> 4);  // + c*32 per k-tile

  // -------- weight burst: whole layer into registers, PINNED for all CH steps ---
  bf16x8 ihf[4][4], hhf[4][4];
  if (L == 0) {
#pragma unroll
    for (int g = 0; g < 4; ++g)
      ihf[g][0] = pinf(*(const bf16x8*)(wp_ih + ((size_t)(g * 8 + w) * 64 + l) * 8));
  } else {
#pragma unroll
    for (int g = 0; g < 4; ++g)
#pragma unroll
      for (int c = 0; c < 4; ++c)
        ihf[g][c] = pinf(*(const bf16x8*)(wp_ih + ((size_t)((g * 8 + w) * 4 + c) * 64 + l) * 8));
  }
#pragma unroll
  for (int g = 0; g < 4; ++g)
#pragma unroll
    for (int c = 0; c < 4; ++c)
      hhf[g][c] = pinf(*(const bf16x8*)(wp_hh + ((size_t)((g * 8 + w) * 4 + c) * 64 + l) * 8));

  // -------- input fragments for step 0 (prefetch discipline starts here) --------
  bf16x8 inF[4], inFn[4];
  if (L == 0) {
    inF[0] = *(const bf16x8*)(x0p + (((size_t)(k * CH) * NTILE + b) * 64 + l) * 8);
    inFn[0] = inF[0];
  } else {
#pragma unroll
    for (int c = 0; c < 4; ++c) {
      inF[c] = *(const bf16x8*)(buf + fragoff + c * 32);
      inFn[c] = inF[c];
    }
  }

  for (int tt = 0; tt < CH; ++tt) {
    const int t = k * CH + tt;
    BAR();  // h(tt-1) writes visible; all reads of slot tt already drained
    if (L == 2) {
      if (tt > 0)
        head_step(b, t - 1, buf + (tt - 1) * 2176, wmS, waS, vS, bmv, bav, out);
    }
    const unsigned short* ahb = (tt == 0) ? carry : buf + (tt - 1) * 2176;
    bf16x8 ah[4];
#pragma unroll
    for (int c = 0; c < 4; ++c) ah[c] = *(const bf16x8*)(ahb + fragoff + c * 32);
    // prefetch next step's input (slot tt+1 — not written until step tt+1)
    if (tt < CH - 1) {
      if (L == 0) {
        inFn[0] = *(const bf16x8*)(x0p + (((size_t)(t + 1) * NTILE + b) * 64 + l) * 8);
      } else {
#pragma unroll
        for (int c = 0; c < 4; ++c)
          inFn[c] = *(const bf16x8*)(buf + (tt + 1) * 2176 + fragoff + c * 32);
      }
    }
    f32x4 acc[4];
#pragma unroll
    for (int g = 0; g < 4; ++g) { float bb = bia[g]; f32x4 z = {bb, bb, bb, bb}; acc[g] = z; }
    if (L == 0) {
#pragma unroll
      for (int g = 0; g < 4; ++g) acc[g] = MFMA(inF[0], ihf[g][0], acc[g]);
    } else {
#pragma unroll
      for (int c = 0; c < 4; ++c)
#pragma unroll
        for (int g = 0; g < 4; ++g) acc[g] = MFMA(inF[c], ihf[g][c], acc[g]);
    }
#pragma unroll
    for (int c = 0; c < 4; ++c)
#pragma unroll
      for (int g = 0; g < 4; ++g) acc[g] = MFMA(ah[c], hhf[g][c], acc[g]);
#pragma unroll
    for (int r = 0; r < 4; ++r) {
      float ig = sigm(acc[0][r]);
      float fg = sigm(acc[1][r]);
      float gt = tanh_(acc[2][r]);
      float og = sigm(acc[3][r]);
      cc[r] = fg * cc[r] + ig * gt;
      float h = og * tanh_(cc[r]);
      unsigned short hb = f2bf(h);
      buf[tt * 2176 + (row0 + r) * 136 + j] = hb;
      if (tt == CH - 1) carry[(row0 + r) * 136 + j] = hb;
    }
#pragma unroll
    for (int c = 0; c < 4; ++c) inF[c] = inFn[c];
  }
  if (L == 2) {
    BAR();  // make h2(CH-1) visible for the final head
    head_step(b, k * CH + CH - 1, buf + (CH - 1) * 2176, wmS, waS, vS, bmv, bav, out);
  }
}

__global__ __launch_bounds__(NTHREADS, 2) void lstm_seq_kern(
    const unsigned short* __restrict__ wp_ih0, const unsigned short* __restrict__ wp_hh0,
    const unsigned short* __restrict__ wp_ih1, const unsigned short* __restrict__ wp_hh1,
    const unsigned short* __restrict__ wp_ih2, const unsigned short* __restrict__ wp_hh2,
    const unsigned short* __restrict__ x0p,
    const float* __restrict__ b0, const float* __restrict__ b1, const float* __restrict__ b2,
    const float* __restrict__ Wm, const float* __restrict__ bm,
    const float* __restrict__ Wa, const float* __restrict__ ba,
    const float* __restrict__ v, float* __restrict__ out) {
  __shared__ unsigned short bufS[CH * 2176];    // in-place h-chunk buffer (139 KB)
  __shared__ unsigned short carryS[3 * 2176];   // per-layer h carry (13 KB)
  __shared__ float wmS[128], waS[128], vS[16];

  const int tid = threadIdx.x;
  const int b = blockIdx.x;
  const int l = tid & 63;
  const int w = tid >> 6;
  const int j = w * 16 + (l & 15);

  for (int i = tid; i < 3 * 2176; i += NTHREADS) carryS[i] = 0;
  if (tid < 128) { wmS[tid] = Wm[tid]; waS[tid] = Wa[tid]; }
  if (tid < 16) vS[tid] = v[b * BPW + tid];

  float bia0[4], bia1[4], bia2[4];
#pragma unroll
  for (int g = 0; g < 4; ++g) {
    bia0[g] = b0[g * 128 + j];
    bia1[g] = b1[g * 128 + j];
    bia2[g] = b2[g * 128 + j];
  }
  float cc0[4] = {0, 0, 0, 0}, cc1[4] = {0, 0, 0, 0}, cc2[4] = {0, 0, 0, 0};
  const float bmv = bm[0], bav = ba[0];

  // Laundered weight base pointers: block LICM from hoisting bursts out of the
  // chunk loop (3 layers of weights can't all be register-resident at once).
  size_t p_ih0 = (size_t)wp_ih0, p_hh0 = (size_t)wp_hh0;
  size_t p_ih1 = (size_t)wp_ih1, p_hh1 = (size_t)wp_hh1;
  size_t p_ih2 = (size_t)wp_ih2, p_hh2 = (size_t)wp_hh2;

  __syncthreads();

  for (int k = 0; k < NCH; ++k) {
    asm volatile("" : "+s"(p_ih0), "+s"(p_hh0), "+s"(p_ih1), "+s"(p_hh1),
                      "+s"(p_ih2), "+s"(p_hh2));
    scan_chunk<0>(k, b, (const unsigned short*)p_ih0, (const unsigned short*)p_hh0,
                  x0p, bufS, carryS, cc0, bia0, wmS, waS, vS, bmv, bav, out);
    scan_chunk<1>(k, b, (const unsigned short*)p_ih1, (const unsigned short*)p_hh1,
                  x0p, bufS, carryS + 2176, cc1, bia1, wmS, waS, vS, bmv, bav, out);
    scan_chunk<2>(k, b, (const unsigned short*)p_ih2, (const unsigned short*)p_hh2,
                  x0p, bufS, carryS + 4352, cc2, bia2, wmS, waS, vS, bmv, bav, out);
  }
}

extern "C" void kernel_launch(void* const* d_in, const int* in_sizes, int n_in,
                              void* d_out, int out_size, void* d_ws, size_t ws_size,
                              hipStream_t stream) {
  const float* x_cont    = (const float*)d_in[0];
  const int*   idx_shops = (const int*)d_in[1];
  const int*   idx_items = (const int*)d_in[2];
  const float* v         = (const float*)d_in[3];
  const float* emb_shops = (const float*)d_in[4];
  const float* emb_items = (const float*)d_in[5];
  const float* Wih0 = (const float*)d_in[6];
  const float* Whh0 = (const float*)d_in[7];
  const float* b0   = (const float*)d_in[8];
  const float* Wih1 = (const float*)d_in[9];
  const float* Whh1 = (const float*)d_in[10];
  const float* b1   = (const float*)d_in[11];
  const float* Wih2 = (const float*)d_in[12];
  const float* Whh2 = (const float*)d_in[13];
  const float* b2   = (const float*)d_in[14];
  const float* Wm   = (const float*)d_in[15];
  const float* bm   = (const float*)d_in[16];
  const float* Wa   = (const float*)d_in[17];
  const float* ba   = (const float*)d_in[18];
  float* out = (float*)d_out;

  unsigned short* ws = (unsigned short*)d_ws;
  unsigned short* wp_ih0 = ws;                  // 32*1*64*8   = 16384 el
  unsigned short* wp_hh0 = wp_ih0 + 16384;      // 32*4*64*8   = 65536 el
  unsigned short* wp_ih1 = wp_hh0 + 65536;
  unsigned short* wp_hh1 = wp_ih1 + 65536;
  unsigned short* wp_ih2 = wp_hh1 + 65536;
  unsigned short* wp_hh2 = wp_ih2 + 65536;
  unsigned short* x0p    = wp_hh2 + 65536;      // 512*32*64*8 = 8388608 el (total 17.5 MB)

  pack_w_kern<<<8, 256, 0, stream>>>(Wih0, wp_ih0, 22, 1);
  pack_w_kern<<<32, 256, 0, stream>>>(Whh0, wp_hh0, 128, 4);
  pack_w_kern<<<32, 256, 0, stream>>>(Wih1, wp_ih1, 128, 4);
  pack_w_kern<<<32, 256, 0, stream>>>(Whh1, wp_hh1, 128, 4);
  pack_w_kern<<<32, 256, 0, stream>>>(Wih2, wp_ih2, 128, 4);
  pack_w_kern<<<32, 256, 0, stream>>>(Whh2, wp_hh2, 128, 4);
  pack_x0_kern<<<4096, 256, 0, stream>>>(x_cont, idx_shops, idx_items,
                                         emb_shops, emb_items, x0p);
  lstm_seq_kern<<<NTILE, NTHREADS, 0, stream>>>(wp_ih0, wp_hh0, wp_ih1, wp_hh1,
                                                wp_ih2, wp_hh2, x0p,
                                                b0, b1, b2, Wm, bm, Wa, ba, v, out);
}

// Round 7
// 1525.656 us; speedup vs baseline: 1.0740x; 1.0740x over previous
//
#include <hip/hip_runtime.h>
#include <hip/hip_bf16.h>

#define TT 512
#define NWGS 128       // 128 WGs x 4 batch rows
#define NTHREADS 512
#define CH 64          // steps per chunk
#define NCH 8          // 512/64

typedef __bf16 bf16x8 __attribute__((ext_vector_type(8)));
typedef float f32x4 __attribute__((ext_vector_type(4)));
typedef unsigned int uint4v __attribute__((ext_vector_type(4)));

#define MFMA(a, b, c) __builtin_amdgcn_mfma_f32_16x16x32_bf16((a), (b), (c), 0, 0, 0)
// Raw barrier: LDS drain only; global loads stay in flight.
#define BAR() asm volatile("s_waitcnt lgkmcnt(0)\n\ts_barrier" ::: "memory")

__device__ __forceinline__ unsigned short f2bf(float f) {
  unsigned int u = __float_as_uint(f);
  u = u + 0x7FFFu + ((u >> 16) & 1u);
  return (unsigned short)(u >> 16);
}
__device__ __forceinline__ float bf2f(unsigned short s) {
  return __uint_as_float(((unsigned int)s) << 16);
}
__device__ __forceinline__ float sigm(float x) {
  return __builtin_amdgcn_rcpf(1.f + __builtin_amdgcn_exp2f(-1.44269504f * x));
}
__device__ __forceinline__ float tanh_(float x) {
  return 1.f - 2.f * __builtin_amdgcn_rcpf(1.f + __builtin_amdgcn_exp2f(2.88539008f * x));
}
__device__ __forceinline__ float softplus_(float x) {
  if (x > 15.f) return x;
  float e = __builtin_amdgcn_exp2f(1.44269504f * x);
  return 0.69314718f * __builtin_amdgcn_logf(1.f + e);
}

// Pin a fragment in VGPRs (effective only if the VGPR budget allows residency).
__device__ __forceinline__ bf16x8 pinf(bf16x8 x) {
  uint4v u = __builtin_bit_cast(uint4v, x);
  asm volatile("" : "+v"(u));
  return __builtin_bit_cast(bf16x8, u);
}

// Pack a [512][K] f32 weight matrix into bf16 B-fragment order:
// dst[((tau*ktiles + c)*64 + l)*8 + i] = W[tau*16 + (l&15)][c*32 + 8*(l>>4) + i]
__global__ void pack_w_kern(const float* __restrict__ src, unsigned short* __restrict__ dst,
                            int K, int ktiles) {
  int tid = blockIdx.x * 256 + threadIdx.x;
  int total = 32 * ktiles * 64;
  if (tid >= total) return;
  int l = tid & 63;
  int c = (tid >> 6) % ktiles;
  int tau = tid / (64 * ktiles);
  int n = tau * 16 + (l & 15);
  int k0 = c * 32 + 8 * (l >> 4);
  unsigned short o[8];
#pragma unroll
  for (int i = 0; i < 8; ++i) {
    int k = k0 + i;
    float v = (k < K) ? src[n * K + k] : 0.f;
    o[i] = f2bf(v);
  }
  *(uint4v*)(dst + (size_t)tid * 8) = *(const uint4v*)o;
}

// Build x0 (concat cont feats + embeddings), bf16, A-fragment order over 32
// 16-row batch tiles, K padded 22->32 (layout unchanged from previous rounds).
__global__ void pack_x0_kern(const float* __restrict__ xc, const int* __restrict__ idxs,
                             const int* __restrict__ idxi, const float* __restrict__ es,
                             const float* __restrict__ ei, unsigned short* __restrict__ dst) {
  int tid = blockIdx.x * 256 + threadIdx.x;
  if (tid >= TT * 32 * 64) return;
  int l = tid & 63;
  int b = (tid >> 6) & 31;
  int t = tid >> 11;
  int bi = b * 16 + (l & 15);
  int k0 = 8 * (l >> 4);
  int si = idxs[bi * TT + t];
  int it = idxi[bi * TT + t];
  const float* xr = xc + ((size_t)bi * TT + t) * 12;
  unsigned short o[8];
#pragma unroll
  for (int i = 0; i < 8; ++i) {
    int k = k0 + i;
    float v;
    if (k < 12)      v = xr[k];
    else if (k < 17) v = es[si * 5 + (k - 12)];
    else if (k < 22) v = ei[it * 5 + (k - 17)];
    else             v = 0.f;
    o[i] = f2bf(v);
  }
  *(uint4v*)(dst + (size_t)tid * 8) = *(const uint4v*)o;
}

// Gaussian head for one step; reads compact h2 slot [4][136]. 64 threads.
__device__ __forceinline__ void head_step(
    int b, int t, const unsigned short* slotbase,
    const float* wmS, const float* waS, const float* vS,
    float bmv, float bav, float* out) {
  const int tid = threadIdx.x;
  if (tid >= 64) return;
  int s_ = tid & 7, hd = (tid >> 3) & 1, bi = tid >> 4;  // bi 0..3
  const float* wv = hd ? waS : wmS;
  const unsigned short* hrow = slotbase + bi * 136 + s_ * 16;
  float part = 0.f;
#pragma unroll
  for (int kk = 0; kk < 16; ++kk) part += bf2f(hrow[kk]) * wv[s_ * 16 + kk];
  part += __shfl_xor(part, 1);
  part += __shfl_xor(part, 2);
  part += __shfl_xor(part, 4);
  if (s_ == 0) {
    float val = part + (hd ? bav : bmv);
    if (hd) val = softplus_(val);
    out[(((size_t)(b * 4 + bi)) * TT + t) * 2 + hd] = val * vS[bi];
  }
}

// One layer's scan over one chunk. Weights pinned in VGPRs for the whole chunk.
// Compact h slots [4][136]; A-frag rows duplicated via (l&3). Epilogue is
// shuffle-compacted to 1 cell/lane: lane l owns cell (bi=l>>4, j=w*16+(l&15)).
template<int L>
__device__ __forceinline__ void scan_chunk(
    int k, int b, const unsigned short* wp_ih, const unsigned short* wp_hh,
    const unsigned short* x0p, unsigned short* buf, unsigned short* carry,
    float& cc, const float (&bia)[4],
    const float* wmS, const float* waS, const float* vS,
    float bmv, float bav, float* out) {
  const int tid = threadIdx.x;
  const int l = tid & 63;
  const int w = tid >> 6;
  const int j = w * 16 + (l & 15);
  const int afrag = (l & 3) * 136 + 8 * (l >> 4);  // + c*32 per k-tile (dup rows)
  const int xlane = (l & 48) | ((b & 3) * 4 + (l & 3));  // row-in-16-tile remap

  // -------- weight burst: whole layer into registers, pinned for all CH steps --
  bf16x8 ihf[4][4], hhf[4][4];
  if (L == 0) {
#pragma unroll
    for (int g = 0; g < 4; ++g)
      ihf[g][0] = pinf(*(const bf16x8*)(wp_ih + ((size_t)(g * 8 + w) * 64 + l) * 8));
  } else {
#pragma unroll
    for (int g = 0; g < 4; ++g)
#pragma unroll
      for (int c = 0; c < 4; ++c)
        ihf[g][c] = pinf(*(const bf16x8*)(wp_ih + ((size_t)((g * 8 + w) * 4 + c) * 64 + l) * 8));
  }
#pragma unroll
  for (int g = 0; g < 4; ++g)
#pragma unroll
    for (int c = 0; c < 4; ++c)
      hhf[g][c] = pinf(*(const bf16x8*)(wp_hh + ((size_t)((g * 8 + w) * 4 + c) * 64 + l) * 8));

  // -------- input fragments for step 0 --------
  bf16x8 inF[4], inFn[4];
  if (L == 0) {
    inF[0] = *(const bf16x8*)(x0p + (((size_t)(k * CH) * 32 + (b >> 2)) * 64 + xlane) * 8);
    inFn[0] = inF[0];
  } else {
#pragma unroll
    for (int c = 0; c < 4; ++c) {
      inF[c] = *(const bf16x8*)(buf + afrag + c * 32);
      inFn[c] = inF[c];
    }
  }

  for (int tt = 0; tt < CH; ++tt) {
    const int t = k * CH + tt;
    BAR();  // h(tt-1) writes visible; all reads of slot tt drained
    if (L == 2 && tt > 0)
      head_step(b, t - 1, buf + (tt - 1) * 544, wmS, waS, vS, bmv, bav, out);
    const unsigned short* ahb = (tt == 0) ? carry : buf + (tt - 1) * 544;
    bf16x8 ah[4];
#pragma unroll
    for (int c = 0; c < 4; ++c) ah[c] = *(const bf16x8*)(ahb + afrag + c * 32);
    // prefetch next step's input (slot tt+1 — not written until step tt+1)
    if (tt < CH - 1) {
      if (L == 0) {
        inFn[0] = *(const bf16x8*)(x0p + (((size_t)(t + 1) * 32 + (b >> 2)) * 64 + xlane) * 8);
      } else {
#pragma unroll
        for (int c = 0; c < 4; ++c)
          inFn[c] = *(const bf16x8*)(buf + (tt + 1) * 544 + afrag + c * 32);
      }
    }
    f32x4 acc[4];
#pragma unroll
    for (int g = 0; g < 4; ++g) { float bb = bia[g]; f32x4 z = {bb, bb, bb, bb}; acc[g] = z; }
    if (L == 0) {
#pragma unroll
      for (int g = 0; g < 4; ++g) acc[g] = MFMA(inF[0], ihf[g][0], acc[g]);
    } else {
#pragma unroll
      for (int c = 0; c < 4; ++c)
#pragma unroll
        for (int g = 0; g < 4; ++g) acc[g] = MFMA(inF[c], ihf[g][c], acc[g]);
    }
#pragma unroll
    for (int c = 0; c < 4; ++c)
#pragma unroll
      for (int g = 0; g < 4; ++g) acc[g] = MFMA(ah[c], hhf[g][c], acc[g]);

    // -------- shuffle-compact: real rows live in lanes 0-15's 4 acc slots ------
    float gv[4];
    const int src = l & 15;
    const int r_ = l >> 4;
#pragma unroll
    for (int g = 0; g < 4; ++g) {
      float v0 = __shfl(acc[g][0], src);
      float v1 = __shfl(acc[g][1], src);
      float v2 = __shfl(acc[g][2], src);
      float v3 = __shfl(acc[g][3], src);
      float va = (r_ & 1) ? v1 : v0;
      float vb = (r_ & 1) ? v3 : v2;
      gv[g] = (r_ & 2) ? vb : va;
    }
    float ig = sigm(gv[0]);
    float fg = sigm(gv[1]);
    float gt = tanh_(gv[2]);
    float og = sigm(gv[3]);
    cc = fg * cc + ig * gt;
    float h = og * tanh_(cc);
    unsigned short hb = f2bf(h);
    buf[tt * 544 + r_ * 136 + j] = hb;
    if (tt == CH - 1) carry[r_ * 136 + j] = hb;
#pragma unroll
    for (int c = 0; c < 4; ++c) inF[c] = inFn[c];
  }
  if (L == 2) {
    BAR();
    head_step(b, k * CH + CH - 1, buf + (CH - 1) * 544, wmS, waS, vS, bmv, bav, out);
  }
}

__global__ __launch_bounds__(NTHREADS, 1) void lstm_seq4_kern(
    const unsigned short* __restrict__ wp_ih0, const unsigned short* __restrict__ wp_hh0,
    const unsigned short* __restrict__ wp_ih1, const unsigned short* __restrict__ wp_hh1,
    const unsigned short* __restrict__ wp_ih2, const unsigned short* __restrict__ wp_hh2,
    const unsigned short* __restrict__ x0p,
    const float* __restrict__ b0, const float* __restrict__ b1, const float* __restrict__ b2,
    const float* __restrict__ Wm, const float* __restrict__ bm,
    const float* __restrict__ Wa, const float* __restrict__ ba,
    const float* __restrict__ v, float* __restrict__ out) {
  __shared__ unsigned short bufS[CH * 544];    // compact h-chunk buffer (69.6 KB)
  __shared__ unsigned short carryS[3 * 544];   // per-layer h carry
  __shared__ float wmS[128], waS[128], vS[4];

  const int tid = threadIdx.x;
  const int b = blockIdx.x;      // 0..127, batch rows [b*4, b*4+4)
  const int l = tid & 63;
  const int w = tid >> 6;
  const int j = w * 16 + (l & 15);

  for (int i = tid; i < 3 * 544; i += NTHREADS) carryS[i] = 0;
  if (tid < 128) { wmS[tid] = Wm[tid]; waS[tid] = Wa[tid]; }
  if (tid < 4) vS[tid] = v[b * 4 + tid];

  float bia0[4], bia1[4], bia2[4];
#pragma unroll
  for (int g = 0; g < 4; ++g) {
    bia0[g] = b0[g * 128 + j];
    bia1[g] = b1[g * 128 + j];
    bia2[g] = b2[g * 128 + j];
  }
  float cc0 = 0.f, cc1 = 0.f, cc2 = 0.f;
  const float bmv = bm[0], bav = ba[0];

  // Laundered weight base pointers: block LICM of bursts out of the chunk loop.
  size_t p_ih0 = (size_t)wp_ih0, p_hh0 = (size_t)wp_hh0;
  size_t p_ih1 = (size_t)wp_ih1, p_hh1 = (size_t)wp_hh1;
  size_t p_ih2 = (size_t)wp_ih2, p_hh2 = (size_t)wp_hh2;

  __syncthreads();

  for (int k = 0; k < NCH; ++k) {
    asm volatile("" : "+s"(p_ih0), "+s"(p_hh0), "+s"(p_ih1), "+s"(p_hh1),
                      "+s"(p_ih2), "+s"(p_hh2));
    scan_chunk<0>(k, b, (const unsigned short*)p_ih0, (const unsigned short*)p_hh0,
                  x0p, bufS, carryS, cc0, bia0, wmS, waS, vS, bmv, bav, out);
    scan_chunk<1>(k, b, (const unsigned short*)p_ih1, (const unsigned short*)p_hh1,
                  x0p, bufS, carryS + 544, cc1, bia1, wmS, waS, vS, bmv, bav, out);
    scan_chunk<2>(k, b, (const unsigned short*)p_ih2, (const unsigned short*)p_hh2,
                  x0p, bufS, carryS + 1088, cc2, bia2, wmS, waS, vS, bmv, bav, out);
  }
}

extern "C" void kernel_launch(void* const* d_in, const int* in_sizes, int n_in,
                              void* d_out, int out_size, void* d_ws, size_t ws_size,
                              hipStream_t stream) {
  const float* x_cont    = (const float*)d_in[0];
  const int*   idx_shops = (const int*)d_in[1];
  const int*   idx_items = (const int*)d_in[2];
  const float* v         = (const float*)d_in[3];
  const float* emb_shops = (const float*)d_in[4];
  const float* emb_items = (const float*)d_in[5];
  const float* Wih0 = (const float*)d_in[6];
  const float* Whh0 = (const float*)d_in[7];
  const float* b0   = (const float*)d_in[8];
  const float* Wih1 = (const float*)d_in[9];
  const float* Whh1 = (const float*)d_in[10];
  const float* b1   = (const float*)d_in[11];
  const float* Wih2 = (const float*)d_in[12];
  const float* Whh2 = (const float*)d_in[13];
  const float* b2   = (const float*)d_in[14];
  const float* Wm   = (const float*)d_in[15];
  const float* bm   = (const float*)d_in[16];
  const float* Wa   = (const float*)d_in[17];
  const float* ba   = (const float*)d_in[18];
  float* out = (float*)d_out;

  unsigned short* ws = (unsigned short*)d_ws;
  unsigned short* wp_ih0 = ws;                  // 32*1*64*8   = 16384 el
  unsigned short* wp_hh0 = wp_ih0 + 16384;      // 32*4*64*8   = 65536 el
  unsigned short* wp_ih1 = wp_hh0 + 65536;
  unsigned short* wp_hh1 = wp_ih1 + 65536;
  unsigned short* wp_ih2 = wp_hh1 + 65536;
  unsigned short* wp_hh2 = wp_ih2 + 65536;
  unsigned short* x0p    = wp_hh2 + 65536;      // 512*32*64*8 = 8388608 el (17.5 MB total)

  pack_w_kern<<<8, 256, 0, stream>>>(Wih0, wp_ih0, 22, 1);
  pack_w_kern<<<32, 256, 0, stream>>>(Whh0, wp_hh0, 128, 4);
  pack_w_kern<<<32, 256, 0, stream>>>(Wih1, wp_ih1, 128, 4);
  pack_w_kern<<<32, 256, 0, stream>>>(Whh1, wp_hh1, 128, 4);
  pack_w_kern<<<32, 256, 0, stream>>>(Wih2, wp_ih2, 128, 4);
  pack_w_kern<<<32, 256, 0, stream>>>(Whh2, wp_hh2, 128, 4);
  pack_x0_kern<<<4096, 256, 0, stream>>>(x_cont, idx_shops, idx_items,
                                         emb_shops, emb_items, x0p);
  lstm_seq4_kern<<<NWGS, NTHREADS, 0, stream>>>(wp_ih0, wp_hh0, wp_ih1, wp_hh1,
                                                wp_ih2, wp_hh2, x0p,
                                                b0, b1, b2, Wm, bm, Wa, ba, v, out);
}

// Round 8
// 1502.703 us; speedup vs baseline: 1.0904x; 1.0153x over previous
//
#include <hip/hip_runtime.h>
#include <hip/hip_bf16.h>

#define TT 512
#define NWGS 128       // 128 WGs x 4 batch rows
#define NTHREADS 512
#define CH 64          // steps per chunk
#define NCH 8          // 512/64
#define SLOT 576       // shorts per h slot: 4 rows x 144 (288B row stride: banks 0/8/16/24)
#define RSTR 144

typedef __bf16 bf16x8 __attribute__((ext_vector_type(8)));
typedef float f32x4 __attribute__((ext_vector_type(4)));
typedef unsigned int uint4v __attribute__((ext_vector_type(4)));

#define MFMA(a, b, c) __builtin_amdgcn_mfma_f32_16x16x32_bf16((a), (b), (c), 0, 0, 0)
// Raw barrier: LDS drain only; global loads stay in flight.
#define BAR() asm volatile("s_waitcnt lgkmcnt(0)\n\ts_barrier" ::: "memory")

__device__ __forceinline__ unsigned short f2bf(float f) {
  unsigned int u = __float_as_uint(f);
  u = u + 0x7FFFu + ((u >> 16) & 1u);
  return (unsigned short)(u >> 16);
}
__device__ __forceinline__ float bf2f(unsigned short s) {
  return __uint_as_float(((unsigned int)s) << 16);
}
__device__ __forceinline__ float sigm(float x) {
  return __builtin_amdgcn_rcpf(1.f + __builtin_amdgcn_exp2f(-1.44269504f * x));
}
__device__ __forceinline__ float tanh_(float x) {
  return 1.f - 2.f * __builtin_amdgcn_rcpf(1.f + __builtin_amdgcn_exp2f(2.88539008f * x));
}
__device__ __forceinline__ float softplus_(float x) {
  if (x > 15.f) return x;
  float e = __builtin_amdgcn_exp2f(1.44269504f * x);
  return 0.69314718f * __builtin_amdgcn_logf(1.f + e);
}

// Pin a fragment in VGPRs (effective now that waves_per_eu(2,2) allows 256 VGPRs).
__device__ __forceinline__ bf16x8 pinf(bf16x8 x) {
  uint4v u = __builtin_bit_cast(uint4v, x);
  asm volatile("" : "+v"(u));
  return __builtin_bit_cast(bf16x8, u);
}

// Pack a [512][K] f32 weight matrix into bf16 B-fragment order:
// dst[((tau*ktiles + c)*64 + l)*8 + i] = W[tau*16 + (l&15)][c*32 + 8*(l>>4) + i]
__global__ void pack_w_kern(const float* __restrict__ src, unsigned short* __restrict__ dst,
                            int K, int ktiles) {
  int tid = blockIdx.x * 256 + threadIdx.x;
  int total = 32 * ktiles * 64;
  if (tid >= total) return;
  int l = tid & 63;
  int c = (tid >> 6) % ktiles;
  int tau = tid / (64 * ktiles);
  int n = tau * 16 + (l & 15);
  int k0 = c * 32 + 8 * (l >> 4);
  unsigned short o[8];
#pragma unroll
  for (int i = 0; i < 8; ++i) {
    int k = k0 + i;
    float v = (k < K) ? src[n * K + k] : 0.f;
    o[i] = f2bf(v);
  }
  *(uint4v*)(dst + (size_t)tid * 8) = *(const uint4v*)o;
}

// Build x0 (concat cont feats + embeddings), bf16, A-fragment order over 32
// 16-row batch tiles, K padded 22->32.
__global__ void pack_x0_kern(const float* __restrict__ xc, const int* __restrict__ idxs,
                             const int* __restrict__ idxi, const float* __restrict__ es,
                             const float* __restrict__ ei, unsigned short* __restrict__ dst) {
  int tid = blockIdx.x * 256 + threadIdx.x;
  if (tid >= TT * 32 * 64) return;
  int l = tid & 63;
  int b = (tid >> 6) & 31;
  int t = tid >> 11;
  int bi = b * 16 + (l & 15);
  int k0 = 8 * (l >> 4);
  int si = idxs[bi * TT + t];
  int it = idxi[bi * TT + t];
  const float* xr = xc + ((size_t)bi * TT + t) * 12;
  unsigned short o[8];
#pragma unroll
  for (int i = 0; i < 8; ++i) {
    int k = k0 + i;
    float v;
    if (k < 12)      v = xr[k];
    else if (k < 17) v = es[si * 5 + (k - 12)];
    else if (k < 22) v = ei[it * 5 + (k - 17)];
    else             v = 0.f;
    o[i] = f2bf(v);
  }
  *(uint4v*)(dst + (size_t)tid * 8) = *(const uint4v*)o;
}

// Gaussian head for one step; reads compact h2 slot [4][RSTR]. 64 threads.
__device__ __forceinline__ void head_step(
    int b, int t, const unsigned short* slotbase,
    const float* wmS, const float* waS, const float* vS,
    float bmv, float bav, float* out) {
  const int tid = threadIdx.x;
  if (tid >= 64) return;
  int s_ = tid & 7, hd = (tid >> 3) & 1, bi = tid >> 4;  // bi 0..3
  const float* wv = hd ? waS : wmS;
  const unsigned short* hrow = slotbase + bi * RSTR + s_ * 16;
  float part = 0.f;
#pragma unroll
  for (int kk = 0; kk < 16; ++kk) part += bf2f(hrow[kk]) * wv[s_ * 16 + kk];
  part += __shfl_xor(part, 1);
  part += __shfl_xor(part, 2);
  part += __shfl_xor(part, 4);
  if (s_ == 0) {
    float val = part + (hd ? bav : bmv);
    if (hd) val = softplus_(val);
    out[(((size_t)(b * 4 + bi)) * TT + t) * 2 + hd] = val * vS[bi];
  }
}

// One layer's scan over one chunk. Weights pinned in VGPRs for the whole chunk.
// Compact h slots [4][RSTR]; A-frag rows duplicated via (l&3). Epilogue is
// shuffle-compacted to 1 cell/lane: lane l owns cell (bi=l>>4, j=w*16+(l&15)).
template<int L>
__device__ __forceinline__ void scan_chunk(
    int k, int b, const unsigned short* wp_ih, const unsigned short* wp_hh,
    const unsigned short* x0p, unsigned short* buf, unsigned short* carry,
    float& cc, const float (&bia)[4],
    const float* wmS, const float* waS, const float* vS,
    float bmv, float bav, float* out) {
  const int tid = threadIdx.x;
  const int l = tid & 63;
  const int w = tid >> 6;
  const int j = w * 16 + (l & 15);
  const int afrag = (l & 3) * RSTR + 8 * (l >> 4);  // + c*32 per k-tile (dup rows)
  const int xlane = (l & 48) | ((b & 3) * 4 + (l & 3));  // row-in-16-tile remap

  // -------- weight burst: whole layer into registers, pinned for all CH steps --
  bf16x8 ihf[4][4], hhf[4][4];
  if (L == 0) {
#pragma unroll
    for (int g = 0; g < 4; ++g)
      ihf[g][0] = pinf(*(const bf16x8*)(wp_ih + ((size_t)(g * 8 + w) * 64 + l) * 8));
  } else {
#pragma unroll
    for (int g = 0; g < 4; ++g)
#pragma unroll
      for (int c = 0; c < 4; ++c)
        ihf[g][c] = pinf(*(const bf16x8*)(wp_ih + ((size_t)((g * 8 + w) * 4 + c) * 64 + l) * 8));
  }
#pragma unroll
  for (int g = 0; g < 4; ++g)
#pragma unroll
    for (int c = 0; c < 4; ++c)
      hhf[g][c] = pinf(*(const bf16x8*)(wp_hh + ((size_t)((g * 8 + w) * 4 + c) * 64 + l) * 8));

  // -------- input fragments for step 0 --------
  bf16x8 inF[4], inFn[4];
  if (L == 0) {
    inF[0] = *(const bf16x8*)(x0p + (((size_t)(k * CH) * 32 + (b >> 2)) * 64 + xlane) * 8);
    inFn[0] = inF[0];
  } else {
#pragma unroll
    for (int c = 0; c < 4; ++c) {
      inF[c] = *(const bf16x8*)(buf + afrag + c * 32);
      inFn[c] = inF[c];
    }
  }

  for (int tt = 0; tt < CH; ++tt) {
    const int t = k * CH + tt;
    BAR();  // h(tt-1) writes visible; all reads of slot tt drained
    if (L == 2 && tt > 0)
      head_step(b, t - 1, buf + (tt - 1) * SLOT, wmS, waS, vS, bmv, bav, out);
    const unsigned short* ahb = (tt == 0) ? carry : buf + (tt - 1) * SLOT;
    bf16x8 ah[4];
#pragma unroll
    for (int c = 0; c < 4; ++c) ah[c] = *(const bf16x8*)(ahb + afrag + c * 32);
    // prefetch next step's input (slot tt+1 — not written until step tt+1)
    if (tt < CH - 1) {
      if (L == 0) {
        inFn[0] = *(const bf16x8*)(x0p + (((size_t)(t + 1) * 32 + (b >> 2)) * 64 + xlane) * 8);
      } else {
#pragma unroll
        for (int c = 0; c < 4; ++c)
          inFn[c] = *(const bf16x8*)(buf + (tt + 1) * SLOT + afrag + c * 32);
      }
    }
    f32x4 acc[4];
#pragma unroll
    for (int g = 0; g < 4; ++g) { float bb = bia[g]; f32x4 z = {bb, bb, bb, bb}; acc[g] = z; }
    if (L == 0) {
#pragma unroll
      for (int g = 0; g < 4; ++g) acc[g] = MFMA(inF[0], ihf[g][0], acc[g]);
    } else {
#pragma unroll
      for (int c = 0; c < 4; ++c)
#pragma unroll
        for (int g = 0; g < 4; ++g) acc[g] = MFMA(inF[c], ihf[g][c], acc[g]);
    }
#pragma unroll
    for (int c = 0; c < 4; ++c)
#pragma unroll
      for (int g = 0; g < 4; ++g) acc[g] = MFMA(ah[c], hhf[g][c], acc[g]);

    // -------- shuffle-compact: real rows live in lanes 0-15's 4 acc slots ------
    float gv[4];
    const int src = l & 15;
    const int r_ = l >> 4;
#pragma unroll
    for (int g = 0; g < 4; ++g) {
      float v0 = __shfl(acc[g][0], src);
      float v1 = __shfl(acc[g][1], src);
      float v2 = __shfl(acc[g][2], src);
      float v3 = __shfl(acc[g][3], src);
      float va = (r_ & 1) ? v1 : v0;
      float vb = (r_ & 1) ? v3 : v2;
      gv[g] = (r_ & 2) ? vb : va;
    }
    float ig = sigm(gv[0]);
    float fg = sigm(gv[1]);
    float gt = tanh_(gv[2]);
    float og = sigm(gv[3]);
    cc = fg * cc + ig * gt;
    float h = og * tanh_(cc);
    unsigned short hb = f2bf(h);
    buf[tt * SLOT + r_ * RSTR + j] = hb;
    if (tt == CH - 1) carry[r_ * RSTR + j] = hb;
#pragma unroll
    for (int c = 0; c < 4; ++c) inF[c] = inFn[c];
  }
  if (L == 2) {
    BAR();
    head_step(b, k * CH + CH - 1, buf + (CH - 1) * SLOT, wmS, waS, vS, bmv, bav, out);
  }
}

__global__ void __launch_bounds__(NTHREADS)
__attribute__((amdgpu_waves_per_eu(2, 2)))  // max=2 waves/SIMD -> 256-VGPR budget
lstm_seq4_kern(
    const unsigned short* __restrict__ wp_ih0, const unsigned short* __restrict__ wp_hh0,
    const unsigned short* __restrict__ wp_ih1, const unsigned short* __restrict__ wp_hh1,
    const unsigned short* __restrict__ wp_ih2, const unsigned short* __restrict__ wp_hh2,
    const unsigned short* __restrict__ x0p,
    const float* __restrict__ b0, const float* __restrict__ b1, const float* __restrict__ b2,
    const float* __restrict__ Wm, const float* __restrict__ bm,
    const float* __restrict__ Wa, const float* __restrict__ ba,
    const float* __restrict__ v, float* __restrict__ out) {
  __shared__ unsigned short bufS[CH * SLOT];   // compact h-chunk buffer (73.7 KB)
  __shared__ unsigned short carryS[3 * SLOT];  // per-layer h carry
  __shared__ float wmS[128], waS[128], vS[4];

  const int tid = threadIdx.x;
  const int b = blockIdx.x;      // 0..127, batch rows [b*4, b*4+4)
  const int l = tid & 63;
  const int w = tid >> 6;
  const int j = w * 16 + (l & 15);

  for (int i = tid; i < 3 * SLOT; i += NTHREADS) carryS[i] = 0;
  if (tid < 128) { wmS[tid] = Wm[tid]; waS[tid] = Wa[tid]; }
  if (tid < 4) vS[tid] = v[b * 4 + tid];

  float bia0[4], bia1[4], bia2[4];
#pragma unroll
  for (int g = 0; g < 4; ++g) {
    bia0[g] = b0[g * 128 + j];
    bia1[g] = b1[g * 128 + j];
    bia2[g] = b2[g * 128 + j];
  }
  float cc0 = 0.f, cc1 = 0.f, cc2 = 0.f;
  const float bmv = bm[0], bav = ba[0];

  // Laundered weight base pointers: block LICM of bursts out of the chunk loop.
  size_t p_ih0 = (size_t)wp_ih0, p_hh0 = (size_t)wp_hh0;
  size_t p_ih1 = (size_t)wp_ih1, p_hh1 = (size_t)wp_hh1;
  size_t p_ih2 = (size_t)wp_ih2, p_hh2 = (size_t)wp_hh2;

  __syncthreads();

  for (int k = 0; k < NCH; ++k) {
    asm volatile("" : "+s"(p_ih0), "+s"(p_hh0), "+s"(p_ih1), "+s"(p_hh1),
                      "+s"(p_ih2), "+s"(p_hh2));
    scan_chunk<0>(k, b, (const unsigned short*)p_ih0, (const unsigned short*)p_hh0,
                  x0p, bufS, carryS, cc0, bia0, wmS, waS, vS, bmv, bav, out);
    scan_chunk<1>(k, b, (const unsigned short*)p_ih1, (const unsigned short*)p_hh1,
                  x0p, bufS, carryS + SLOT, cc1, bia1, wmS, waS, vS, bmv, bav, out);
    scan_chunk<2>(k, b, (const unsigned short*)p_ih2, (const unsigned short*)p_hh2,
                  x0p, bufS, carryS + 2 * SLOT, cc2, bia2, wmS, waS, vS, bmv, bav, out);
  }
}

extern "C" void kernel_launch(void* const* d_in, const int* in_sizes, int n_in,
                              void* d_out, int out_size, void* d_ws, size_t ws_size,
                              hipStream_t stream) {
  const float* x_cont    = (const float*)d_in[0];
  const int*   idx_shops = (const int*)d_in[1];
  const int*   idx_items = (const int*)d_in[2];
  const float* v         = (const float*)d_in[3];
  const float* emb_shops = (const float*)d_in[4];
  const float* emb_items = (const float*)d_in[5];
  const float* Wih0 = (const float*)d_in[6];
  const float* Whh0 = (const float*)d_in[7];
  const float* b0   = (const float*)d_in[8];
  const float* Wih1 = (const float*)d_in[9];
  const float* Whh1 = (const float*)d_in[10];
  const float* b1   = (const float*)d_in[11];
  const float* Wih2 = (const float*)d_in[12];
  const float* Whh2 = (const float*)d_in[13];
  const float* b2   = (const float*)d_in[14];
  const float* Wm   = (const float*)d_in[15];
  const float* bm   = (const float*)d_in[16];
  const float* Wa   = (const float*)d_in[17];
  const float* ba   = (const float*)d_in[18];
  float* out = (float*)d_out;

  unsigned short* ws = (unsigned short*)d_ws;
  unsigned short* wp_ih0 = ws;                  // 32*1*64*8   = 16384 el
  unsigned short* wp_hh0 = wp_ih0 + 16384;      // 32*4*64*8   = 65536 el
  unsigned short* wp_ih1 = wp_hh0 + 65536;
  unsigned short* wp_hh1 = wp_ih1 + 65536;
  unsigned short* wp_ih2 = wp_hh1 + 65536;
  unsigned short* wp_hh2 = wp_ih2 + 65536;
  unsigned short* x0p    = wp_hh2 + 65536;      // 512*32*64*8 = 8388608 el (17.5 MB total)

  pack_w_kern<<<8, 256, 0, stream>>>(Wih0, wp_ih0, 22, 1);
  pack_w_kern<<<32, 256, 0, stream>>>(Whh0, wp_hh0, 128, 4);
  pack_w_kern<<<32, 256, 0, stream>>>(Wih1, wp_ih1, 128, 4);
  pack_w_kern<<<32, 256, 0, stream>>>(Whh1, wp_hh1, 128, 4);
  pack_w_kern<<<32, 256, 0, stream>>>(Wih2, wp_ih2, 128, 4);
  pack_w_kern<<<32, 256, 0, stream>>>(Whh2, wp_hh2, 128, 4);
  pack_x0_kern<<<4096, 256, 0, stream>>>(x_cont, idx_shops, idx_items,
                                         emb_shops, emb_items, x0p);
  lstm_seq4_kern<<<NWGS, NTHREADS, 0, stream>>>(wp_ih0, wp_hh0, wp_ih1, wp_hh1,
                                                wp_ih2, wp_hh2, x0p,
                                                b0, b1, b2, Wm, bm, Wa, ba, v, out);
}

// Round 10
// 1428.927 us; speedup vs baseline: 1.1467x; 1.0516x over previous
//
#include <hip/hip_runtime.h>
#include <hip/hip_bf16.h>

#define TT 512
#define NWGS 128       // 128 WGs x 4 batch rows
#define NTHREADS 512
#define CH 64          // steps per chunk
#define NCH 8          // 512/64
#define SLOT 576       // shorts per h slot: 4 rows x 144 (288B row stride)
#define RSTR 144

typedef float f32x4 __attribute__((ext_vector_type(4)));
typedef unsigned int uint4v __attribute__((ext_vector_type(4)));

// Raw barrier: LDS drain only; global loads stay in flight.
#define BAR() asm volatile("s_waitcnt lgkmcnt(0)\n\ts_barrier" ::: "memory")

__device__ __forceinline__ unsigned short f2bf(float f) {
  unsigned int u = __float_as_uint(f);
  u = u + 0x7FFFu + ((u >> 16) & 1u);
  return (unsigned short)(u >> 16);
}
__device__ __forceinline__ float bf2f(unsigned short s) {
  return __uint_as_float(((unsigned int)s) << 16);
}
__device__ __forceinline__ float sigm(float x) {
  return __builtin_amdgcn_rcpf(1.f + __builtin_amdgcn_exp2f(-1.44269504f * x));
}
__device__ __forceinline__ float tanh_(float x) {
  return 1.f - 2.f * __builtin_amdgcn_rcpf(1.f + __builtin_amdgcn_exp2f(2.88539008f * x));
}
__device__ __forceinline__ float softplus_(float x) {
  if (x > 15.f) return x;
  float e = __builtin_amdgcn_exp2f(1.44269504f * x);
  return 0.69314718f * __builtin_amdgcn_logf(1.f + e);
}

// Load a 16B weight fragment and pin it into an AGPR quad (v_accvgpr_write x4,
// once per chunk). AGPRs don't compete with the 128-arch-VGPR budget.
__device__ __forceinline__ uint4v pin_a(const unsigned short* p) {
  uint4v u = *(const uint4v*)p;
  asm volatile("" : "+a"(u));
  return u;
}

// MFMA with A from VGPR (activations) and B from AGPR (resident weights).
// volatile: keep program order among MFMAs; hazard nops added manually since
// the GCN hazard recognizer cannot see inside inline asm.
__device__ __forceinline__ void mfma_va(f32x4& acc, uint4v a, uint4v b) {
  asm volatile("v_mfma_f32_16x16x32_bf16 %0, %1, %2, %0" : "+v"(acc) : "v"(a), "a"(b));
}
// Variant for the LAST write of an accumulator before VALU/ds_swizzle reads:
// trailing s_nop 7 provides the MFMA->VALU-read wait states the compiler
// normally inserts for intrinsic MFMAs.
__device__ __forceinline__ void mfma_va_end(f32x4& acc, uint4v a, uint4v b) {
  asm volatile("v_mfma_f32_16x16x32_bf16 %0, %1, %2, %0\n\ts_nop 7"
               : "+v"(acc) : "v"(a), "a"(b));
}

// Pack a [512][K] f32 weight matrix into bf16 B-fragment order:
// dst[((tau*ktiles + c)*64 + l)*8 + i] = W[tau*16 + (l&15)][c*32 + 8*(l>>4) + i]
__global__ void pack_w_kern(const float* __restrict__ src, unsigned short* __restrict__ dst,
                            int K, int ktiles) {
  int tid = blockIdx.x * 256 + threadIdx.x;
  int total = 32 * ktiles * 64;
  if (tid >= total) return;
  int l = tid & 63;
  int c = (tid >> 6) % ktiles;
  int tau = tid / (64 * ktiles);
  int n = tau * 16 + (l & 15);
  int k0 = c * 32 + 8 * (l >> 4);
  unsigned short o[8];
#pragma unroll
  for (int i = 0; i < 8; ++i) {
    int k = k0 + i;
    float v = (k < K) ? src[n * K + k] : 0.f;
    o[i] = f2bf(v);
  }
  *(uint4v*)(dst + (size_t)tid * 8) = *(const uint4v*)o;
}

// Build x0 (concat cont feats + embeddings), bf16, A-fragment order over 32
// 16-row batch tiles, K padded 22->32.
__global__ void pack_x0_kern(const float* __restrict__ xc, const int* __restrict__ idxs,
                             const int* __restrict__ idxi, const float* __restrict__ es,
                             const float* __restrict__ ei, unsigned short* __restrict__ dst) {
  int tid = blockIdx.x * 256 + threadIdx.x;
  if (tid >= TT * 32 * 64) return;
  int l = tid & 63;
  int b = (tid >> 6) & 31;
  int t = tid >> 11;
  int bi = b * 16 + (l & 15);
  int k0 = 8 * (l >> 4);
  int si = idxs[bi * TT + t];
  int it = idxi[bi * TT + t];
  const float* xr = xc + ((size_t)bi * TT + t) * 12;
  unsigned short o[8];
#pragma unroll
  for (int i = 0; i < 8; ++i) {
    int k = k0 + i;
    float v;
    if (k < 12)      v = xr[k];
    else if (k < 17) v = es[si * 5 + (k - 12)];
    else if (k < 22) v = ei[it * 5 + (k - 17)];
    else             v = 0.f;
    o[i] = f2bf(v);
  }
  *(uint4v*)(dst + (size_t)tid * 8) = *(const uint4v*)o;
}

// Gaussian head for one step; reads compact h2 slot [4][RSTR]. 64 threads.
__device__ __forceinline__ void head_step(
    int b, int t, const unsigned short* slotbase,
    const float* wmS, const float* waS, const float* vS,
    float bmv, float bav, float* out) {
  const int tid = threadIdx.x;
  if (tid >= 64) return;
  int s_ = tid & 7, hd = (tid >> 3) & 1, bi = tid >> 4;  // bi 0..3
  const float* wv = hd ? waS : wmS;
  const unsigned short* hrow = slotbase + bi * RSTR + s_ * 16;
  float part = 0.f;
#pragma unroll
  for (int kk = 0; kk < 16; ++kk) part += bf2f(hrow[kk]) * wv[s_ * 16 + kk];
  part += __shfl_xor(part, 1);
  part += __shfl_xor(part, 2);
  part += __shfl_xor(part, 4);
  if (s_ == 0) {
    float val = part + (hd ? bav : bmv);
    if (hd) val = softplus_(val);
    out[(((size_t)(b * 4 + bi)) * TT + t) * 2 + hd] = val * vS[bi];
  }
}

// One layer's scan over one chunk. Weights AGPR-resident for the whole chunk;
// MFMAs issued as inline asm reading B directly from AGPRs. Compact h slots
// [4][RSTR]; epilogue shuffle-compacted to 1 cell/lane.
template<int L>
__device__ __forceinline__ void scan_chunk(
    int k, int b, const unsigned short* wp_ih, const unsigned short* wp_hh,
    const unsigned short* x0p, unsigned short* buf, unsigned short* carry,
    float& cc, const float (&bia)[4],
    const float* wmS, const float* waS, const float* vS,
    float bmv, float bav, float* out) {
  const int tid = threadIdx.x;
  const int l = tid & 63;
  const int w = tid >> 6;
  const int j = w * 16 + (l & 15);
  const int afrag = (l & 3) * RSTR + 8 * (l >> 4);  // + c*32 per k-tile (dup rows)
  const int xlane = (l & 48) | ((b & 3) * 4 + (l & 3));  // row-in-16-tile remap

  // -------- weight burst: whole layer into AGPRs, resident for all CH steps ----
  uint4v ihf[4][4], hhf[4][4];
  if (L == 0) {
#pragma unroll
    for (int g = 0; g < 4; ++g)
      ihf[g][0] = pin_a(wp_ih + ((size_t)(g * 8 + w) * 64 + l) * 8);
  } else {
#pragma unroll
    for (int g = 0; g < 4; ++g)
#pragma unroll
      for (int c = 0; c < 4; ++c)
        ihf[g][c] = pin_a(wp_ih + ((size_t)((g * 8 + w) * 4 + c) * 64 + l) * 8);
  }
#pragma unroll
  for (int g = 0; g < 4; ++g)
#pragma unroll
    for (int c = 0; c < 4; ++c)
      hhf[g][c] = pin_a(wp_hh + ((size_t)((g * 8 + w) * 4 + c) * 64 + l) * 8);
  asm volatile("s_nop 1");  // VALU(accvgpr_write) -> MFMA B-read wait states

  // -------- input fragments for step 0 --------
  uint4v inF[4], inFn[4];
  if (L == 0) {
    inF[0] = *(const uint4v*)(x0p + (((size_t)(k * CH) * 32 + (b >> 2)) * 64 + xlane) * 8);
    inFn[0] = inF[0];
  } else {
#pragma unroll
    for (int c = 0; c < 4; ++c) {
      inF[c] = *(const uint4v*)(buf + afrag + c * 32);
      inFn[c] = inF[c];
    }
  }

  for (int tt = 0; tt < CH; ++tt) {
    const int t = k * CH + tt;
    BAR();  // h(tt-1) writes visible; all reads of slot tt drained
    if (L == 2 && tt > 0)
      head_step(b, t - 1, buf + (tt - 1) * SLOT, wmS, waS, vS, bmv, bav, out);
    const unsigned short* ahb = (tt == 0) ? carry : buf + (tt - 1) * SLOT;
    uint4v ah[4];
#pragma unroll
    for (int c = 0; c < 4; ++c) ah[c] = *(const uint4v*)(ahb + afrag + c * 32);
    // prefetch next step's input (slot tt+1 — not written until step tt+1)
    if (tt < CH - 1) {
      if (L == 0) {
        inFn[0] = *(const uint4v*)(x0p + (((size_t)(t + 1) * 32 + (b >> 2)) * 64 + xlane) * 8);
      } else {
#pragma unroll
        for (int c = 0; c < 4; ++c)
          inFn[c] = *(const uint4v*)(buf + (tt + 1) * SLOT + afrag + c * 32);
      }
    }
    f32x4 acc[4];
#pragma unroll
    for (int g = 0; g < 4; ++g) { float bb = bia[g]; f32x4 z = {bb, bb, bb, bb}; acc[g] = z; }
    if (L == 0) {
#pragma unroll
      for (int g = 0; g < 4; ++g) mfma_va(acc[g], inF[0], ihf[g][0]);
    } else {
#pragma unroll
      for (int c = 0; c < 4; ++c)
#pragma unroll
        for (int g = 0; g < 4; ++g) mfma_va(acc[g], inF[c], ihf[g][c]);
    }
#pragma unroll
    for (int c = 0; c < 4; ++c)
#pragma unroll
      for (int g = 0; g < 4; ++g) {
        if (c == 3) mfma_va_end(acc[g], ah[c], hhf[g][c]);  // last write: +s_nop 7
        else        mfma_va(acc[g], ah[c], hhf[g][c]);
      }

    // -------- shuffle-compact: real rows live in lanes 0-15's 4 acc slots ------
    float gv[4];
    const int src = l & 15;
    const int r_ = l >> 4;
#pragma unroll
    for (int g = 0; g < 4; ++g) {
      float v0 = __shfl(acc[g][0], src);
      float v1 = __shfl(acc[g][1], src);
      float v2 = __shfl(acc[g][2], src);
      float v3 = __shfl(acc[g][3], src);
      float va = (r_ & 1) ? v1 : v0;
      float vb = (r_ & 1) ? v3 : v2;
      gv[g] = (r_ & 2) ? vb : va;
    }
    float ig = sigm(gv[0]);
    float fg = sigm(gv[1]);
    float gt = tanh_(gv[2]);
    float og = sigm(gv[3]);
    cc = fg * cc + ig * gt;
    float h = og * tanh_(cc);
    unsigned short hb = f2bf(h);
    buf[tt * SLOT + r_ * RSTR + j] = hb;
    if (tt == CH - 1) carry[r_ * RSTR + j] = hb;
#pragma unroll
    for (int c = 0; c < 4; ++c) inF[c] = inFn[c];
  }
  if (L == 2) {
    BAR();
    head_step(b, k * CH + CH - 1, buf + (CH - 1) * SLOT, wmS, waS, vS, bmv, bav, out);
  }
}

__global__ void __launch_bounds__(NTHREADS)
__attribute__((amdgpu_waves_per_eu(2, 2)))
lstm_seq4_kern(
    const unsigned short* __restrict__ wp_ih0, const unsigned short* __restrict__ wp_hh0,
    const unsigned short* __restrict__ wp_ih1, const unsigned short* __restrict__ wp_hh1,
    const unsigned short* __restrict__ wp_ih2, const unsigned short* __restrict__ wp_hh2,
    const unsigned short* __restrict__ x0p,
    const float* __restrict__ b0, const float* __restrict__ b1, const float* __restrict__ b2,
    const float* __restrict__ Wm, const float* __restrict__ bm,
    const float* __restrict__ Wa, const float* __restrict__ ba,
    const float* __restrict__ v, float* __restrict__ out) {
  __shared__ unsigned short bufS[CH * SLOT];   // compact h-chunk buffer (73.7 KB)
  __shared__ unsigned short carryS[3 * SLOT];  // per-layer h carry
  __shared__ float wmS[128], waS[128], vS[4];

  const int tid = threadIdx.x;
  const int b = blockIdx.x;      // 0..127, batch rows [b*4, b*4+4)
  const int l = tid & 63;
  const int w = tid >> 6;
  const int j = w * 16 + (l & 15);

  for (int i = tid; i < 3 * SLOT; i += NTHREADS) carryS[i] = 0;
  if (tid < 128) { wmS[tid] = Wm[tid]; waS[tid] = Wa[tid]; }
  if (tid < 4) vS[tid] = v[b * 4 + tid];

  float bia0[4], bia1[4], bia2[4];
#pragma unroll
  for (int g = 0; g < 4; ++g) {
    bia0[g] = b0[g * 128 + j];
    bia1[g] = b1[g * 128 + j];
    bia2[g] = b2[g * 128 + j];
  }
  float cc0 = 0.f, cc1 = 0.f, cc2 = 0.f;
  const float bmv = bm[0], bav = ba[0];

  // Laundered weight base pointers: block LICM of bursts out of the chunk loop.
  size_t p_ih0 = (size_t)wp_ih0, p_hh0 = (size_t)wp_hh0;
  size_t p_ih1 = (size_t)wp_ih1, p_hh1 = (size_t)wp_hh1;
  size_t p_ih2 = (size_t)wp_ih2, p_hh2 = (size_t)wp_hh2;

  __syncthreads();

  for (int k = 0; k < NCH; ++k) {
    asm volatile("" : "+s"(p_ih0), "+s"(p_hh0), "+s"(p_ih1), "+s"(p_hh1),
                      "+s"(p_ih2), "+s"(p_hh2));
    scan_chunk<0>(k, b, (const unsigned short*)p_ih0, (const unsigned short*)p_hh0,
                  x0p, bufS, carryS, cc0, bia0, wmS, waS, vS, bmv, bav, out);
    scan_chunk<1>(k, b, (const unsigned short*)p_ih1, (const unsigned short*)p_hh1,
                  x0p, bufS, carryS + SLOT, cc1, bia1, wmS, waS, vS, bmv, bav, out);
    scan_chunk<2>(k, b, (const unsigned short*)p_ih2, (const unsigned short*)p_hh2,
                  x0p, bufS, carryS + 2 * SLOT, cc2, bia2, wmS, waS, vS, bmv, bav, out);
  }
}

extern "C" void kernel_launch(void* const* d_in, const int* in_sizes, int n_in,
                              void* d_out, int out_size, void* d_ws, size_t ws_size,
                              hipStream_t stream) {
  const float* x_cont    = (const float*)d_in[0];
  const int*   idx_shops = (const int*)d_in[1];
  const int*   idx_items = (const int*)d_in[2];
  const float* v         = (const float*)d_in[3];
  const float* emb_shops = (const float*)d_in[4];
  const float* emb_items = (const float*)d_in[5];
  const float* Wih0 = (const float*)d_in[6];
  const float* Whh0 = (const float*)d_in[7];
  const float* b0   = (const float*)d_in[8];
  const float* Wih1 = (const float*)d_in[9];
  const float* Whh1 = (const float*)d_in[10];
  const float* b1   = (const float*)d_in[11];
  const float* Wih2 = (const float*)d_in[12];
  const float* Whh2 = (const float*)d_in[13];
  const float* b2   = (const float*)d_in[14];
  const float* Wm   = (const float*)d_in[15];
  const float* bm   = (const float*)d_in[16];
  const float* Wa   = (const float*)d_in[17];
  const float* ba   = (const float*)d_in[18];
  float* out = (float*)d_out;

  unsigned short* ws = (unsigned short*)d_ws;
  unsigned short* wp_ih0 = ws;                  // 32*1*64*8   = 16384 el
  unsigned short* wp_hh0 = wp_ih0 + 16384;      // 32*4*64*8   = 65536 el
  unsigned short* wp_ih1 = wp_hh0 + 65536;
  unsigned short* wp_hh1 = wp_ih1 + 65536;
  unsigned short* wp_ih2 = wp_hh1 + 65536;
  unsigned short* wp_hh2 = wp_ih2 + 65536;
  unsigned short* x0p    = wp_hh2 + 65536;      // 512*32*64*8 = 8388608 el (17.5 MB total)

  pack_w_kern<<<8, 256, 0, stream>>>(Wih0, wp_ih0, 22, 1);
  pack_w_kern<<<32, 256, 0, stream>>>(Whh0, wp_hh0, 128, 4);
  pack_w_kern<<<32, 256, 0, stream>>>(Wih1, wp_ih1, 128, 4);
  pack_w_kern<<<32, 256, 0, stream>>>(Whh1, wp_hh1, 128, 4);
  pack_w_kern<<<32, 256, 0, stream>>>(Wih2, wp_ih2, 128, 4);
  pack_w_kern<<<32, 256, 0, stream>>>(Whh2, wp_hh2, 128, 4);
  pack_x0_kern<<<4096, 256, 0, stream>>>(x_cont, idx_shops, idx_items,
                                         emb_shops, emb_items, x0p);
  lstm_seq4_kern<<<NWGS, NTHREADS, 0, stream>>>(wp_ih0, wp_hh0, wp_ih1, wp_hh1,
                                                wp_ih2, wp_hh2, x0p,
                                                b0, b1, b2, Wm, bm, Wa, ba, v, out);
}